// Round 18
// baseline (145.272 us; speedup 1.0000x reference)
//
#include <hip/hip_runtime.h>

// 2-layer GCN, CSR-gather formulation, v18.
//   Â = D^{-1/2}(A+I)D^{-1/2},  out = Â(relu(Â z W1 + b1))W2 + b2
// layer1: t1b = bf16(Â z); dense: hs = bf16(dinv*(relu(t1b@W1+b1)@W2)) on MFMA;
// layer2: out = gather(hs) + b2.
// v6: CSR via counting sort — zero global atomics. v7: bf16 gather operand.
// v9: operand pre-scaled by dinv. v11: convs fused into finalize.
// v13/14: dense on matrix cores. v15/16: 32-edge MLP, 8x16B gather lanes.
// v17: 4B CSR entries (src:u16|bf16 ew), NPB=64.
// v18: CH 8192->2048. v16's CH=8192 left scatter at G1=196 blocks (<1/CU,
// 5.6% occupancy, 48us — latency-bound on the LDS-cursor chain with no TLP).
// 782 blocks restores ~3 blocks/CU.

#define NPB 64    // nodes per fine bucket (dst & 63 is the in-bucket id)
#define CH  2048  // edges per chunk block in hist/scatter passes

typedef __attribute__((ext_vector_type(8))) short short8v;
typedef __attribute__((ext_vector_type(4))) float f32x4;

__device__ __forceinline__ float4 ld4(const float* p) {
    return *reinterpret_cast<const float4*>(p);
}

// round-to-nearest-even f32 -> bf16 (as ushort in low bits)
__device__ __forceinline__ unsigned bfr(float f) {
    unsigned u = __float_as_uint(f);
    return (u + 0x7FFFu + ((u >> 16) & 1u)) >> 16;
}
// unpack uint (2 bf16) -> 2 f32
__device__ __forceinline__ void bf2(unsigned v, float& lo, float& hi) {
    lo = __uint_as_float(v << 16);
    hi = __uint_as_float(v & 0xFFFF0000u);
}

// exclusive scan of btot[0..NBKT) into LDS bbs[] (blockDim=256, NBKT<=1024)
__device__ __forceinline__ void scan_btot(const int* __restrict__ btot, int NBKT,
                                          int* bbs, int* wtot) {
    int tid = threadIdx.x;
    int v[4];
    int s = 0;
#pragma unroll
    for (int q = 0; q < 4; ++q) {
        int i = 4 * tid + q;
        v[q] = (i < NBKT) ? btot[i] : 0;
        s += v[q];
    }
    int lane = tid & 63, wid = tid >> 6;
    int incl = s;
#pragma unroll
    for (int off = 1; off < 64; off <<= 1) {
        int u = __shfl_up(incl, off, 64);
        if (lane >= off) incl += u;
    }
    if (lane == 63) wtot[wid] = incl;
    __syncthreads();
    int woff = 0;
#pragma unroll
    for (int w = 0; w < 4; ++w) if (w < wid) woff += wtot[w];
    int ex = woff + incl - s;
#pragma unroll
    for (int q = 0; q < 4; ++q) {
        int i = 4 * tid + q;
        if (i < NBKT) bbs[i] = ex;
        ex += v[q];
    }
    __syncthreads();
}

// ---- K1: coarse histogram per chunk (LDS), bucket-major out: hist[b*G1+g] ----
__global__ __launch_bounds__(256) void hist_kernel(const int* __restrict__ dst,
                                                   int* __restrict__ hist,
                                                   int E, int G1, int NBKT) {
    __shared__ int lh[1024];
    for (int i = threadIdx.x; i < NBKT; i += 256) lh[i] = 0;
    __syncthreads();
    int g = blockIdx.x;
    int beg = g * CH, end = min(beg + CH, E);
    for (int j = beg + (int)threadIdx.x; j < end; j += 256)
        atomicAdd(&lh[dst[j] / NPB], 1);
    __syncthreads();
    for (int i = threadIdx.x; i < NBKT; i += 256) hist[(size_t)i * G1 + g] = lh[i];
}

// ---- K2: per-bucket exclusive scan across chunks (in place); btot[b] = total ----
__global__ __launch_bounds__(64) void bscan_kernel(int* __restrict__ hist,
                                                   int* __restrict__ btot, int G1) {
    int b = blockIdx.x;
    int* row = hist + (size_t)b * G1;
    int lane = threadIdx.x;
    int carry = 0;
    for (int g0 = 0; g0 < G1; g0 += 64) {
        int g = g0 + lane;
        int v = (g < G1) ? row[g] : 0;
        int incl = v;
#pragma unroll
        for (int off = 1; off < 64; off <<= 1) {
            int u = __shfl_up(incl, off, 64);
            if (lane >= off) incl += u;
        }
        if (g < G1) row[g] = carry + incl - v;
        carry += __shfl(incl, 63, 64);
    }
    if (lane == 0) btot[b] = carry;
}

// ---- K3: scatter edges into bucket-grouped tmp via LDS cursors (scan fused) ----
__global__ __launch_bounds__(256) void scatter_kernel(const int* __restrict__ src,
                                                      const int* __restrict__ dst,
                                                      const float* __restrict__ ew,
                                                      const int* __restrict__ hist,
                                                      const int* __restrict__ btot,
                                                      int2* __restrict__ tmp,
                                                      int E, int G1, int NBKT) {
    __shared__ int bbs[1024];
    __shared__ int wtot[4];
    __shared__ int cursor[1024];
    scan_btot(btot, NBKT, bbs, wtot);
    int g = blockIdx.x;
    for (int i = threadIdx.x; i < NBKT; i += 256)
        cursor[i] = bbs[i] + hist[(size_t)i * G1 + g];
    __syncthreads();
    int beg = g * CH, end = min(beg + CH, E);
    for (int j = beg + (int)threadIdx.x; j < end; j += 256) {
        int d = dst[j];
        int b = d / NPB;
        int pos = atomicAdd(&cursor[b], 1);
        tmp[pos] = make_int2(((d & (NPB - 1)) << 24) | src[j], __float_as_int(ew[j]));
    }
}

// ---- K4: per-bucket finalize: rowptr, dinv, final CSR u32 {src, bf16 ew}, zs ----
__global__ __launch_bounds__(256) void finalize_kernel(const int2* __restrict__ tmp,
                                                       const int* __restrict__ btot,
                                                       const float* __restrict__ z,
                                                       int* __restrict__ rowptr,
                                                       float* __restrict__ dinv,
                                                       unsigned* __restrict__ csr,
                                                       uint2* __restrict__ zs,
                                                       int n, int E, int NBKT) {
    __shared__ int bbs[1024];
    __shared__ int wsum_[4];
    __shared__ unsigned int hist[NPB];
    __shared__ float dvl[NPB];
    scan_btot(btot, NBKT, bbs, wsum_);
    int b = blockIdx.x;
    int base = bbs[b];
    int cnt  = btot[b];
    int tid  = threadIdx.x;
    if (tid < NPB) hist[tid] = 0;
    __syncthreads();
    // phase A: packed count (bits 24..31) + weighted degree (2^-14 fix, bits 0..23)
    for (int j = tid; j < cnt; j += 256) {
        int2 t = tmp[base + j];
        unsigned dlow = ((unsigned)t.x) >> 24;
        unsigned wfix = (unsigned)(__int_as_float(t.y) * 16384.0f);
        atomicAdd(&hist[dlow], (1u << 24) | wfix);
    }
    __syncthreads();
    // node-level exclusive scan (NPB=64 -> single wave 0)
    if (tid < NPB) {
        unsigned pk = hist[tid];
        int c = (int)(pk >> 24);
        int incl = c;
#pragma unroll
        for (int off = 1; off < 64; off <<= 1) {
            int u = __shfl_up(incl, off, 64);
            if (tid >= off) incl += u;
        }
        int excl = incl - c;
        int node = b * NPB + tid;
        float dv = 0.f;
        if (node < n) {
            rowptr[node] = base + excl;
            float wdeg = (float)(pk & 0xFFFFFFu) * (1.0f / 16384.0f);
            dv = rsqrtf(wdeg + 1.0f);
            dinv[node] = dv;
        }
        dvl[tid]  = dv;
        hist[tid] = (unsigned)excl;   // becomes cursor for phase B
    }
    if (b == 0 && tid == 0) rowptr[n] = E;
    __syncthreads();
    // phase B: place edges within bucket; csr entry = src | bf16(ew)<<16
    for (int j = tid; j < cnt; j += 256) {
        int2 t = tmp[base + j];
        unsigned dlow = ((unsigned)t.x) >> 24;
        unsigned srcv = (unsigned)(t.x & 0xFFFFFF);
        int lr = (int)atomicAdd(&hist[dlow], 1u);
        csr[base + lr] = srcv | (bfr(__int_as_float(t.y)) << 16);
    }
    // phase C (fused convs): zs[node] = bf16(dinv*z[node]) for this block's nodes
    for (int t = tid; t < NPB * 16; t += 256) {
        int li = t >> 4;
        int node = b * NPB + li;
        if (node < n) {
            int k = t & 15;
            float dv = dvl[li];
            float4 f = ld4(z + (size_t)node * 64 + k * 4);
            zs[(size_t)node * 16 + k] =
                make_uint2(bfr(dv * f.x) | (bfr(dv * f.y) << 16),
                           bfr(dv * f.z) | (bfr(dv * f.w) << 16));
        }
    }
}

// ---- gather-aggregate (F=64, bf16 pre-scaled operand): one wave per dst row ----
// Lane l: eg = l>>3 (8 edge subgroups), fq = l&7 (uint4 = 8 bf16 = 16B/lane).
// csr entry u32: src = lo16, bf16 ew = hi16. 32 edges in flight (4-deep).
// out[row] = (BIAS? b : 0) + dv * ( sum_j ew_j * Hp[src_j] + Hp[row] )
// OUTB: write result as bf16 [n][64] (uint4 per lane) instead of f32.
template<bool BIAS, bool OUTB>
__global__ __launch_bounds__(256) void gaggb_kernel(const int* __restrict__ rowptr,
                                                    const unsigned* __restrict__ csr,
                                                    const float* __restrict__ dinv,
                                                    const uint4* __restrict__ Hp4,
                                                    const float* __restrict__ b,
                                                    void* __restrict__ out, int n) {
    int row  = (blockIdx.x * 256 + threadIdx.x) >> 6;
    int lane = threadIdx.x & 63;
    if (row >= n) return;
    int eg = lane >> 3, fq = lane & 7;
    int beg = rowptr[row], end = rowptr[row + 1];
    float dv = dinv[row];

    float a0 = 0.f, a1 = 0.f, a2 = 0.f, a3 = 0.f;
    float a4 = 0.f, a5 = 0.f, a6 = 0.f, a7 = 0.f;
    float f0, f1, f2, f3, f4, f5, f6, f7;

#define ACCUM(V, W)                                            \
    bf2((V).x, f0, f1); bf2((V).y, f2, f3);                    \
    bf2((V).z, f4, f5); bf2((V).w, f6, f7);                    \
    a0 += (W) * f0; a1 += (W) * f1; a2 += (W) * f2; a3 += (W) * f3; \
    a4 += (W) * f4; a5 += (W) * f5; a6 += (W) * f6; a7 += (W) * f7;

    int j = beg;
    for (; j + 32 <= end; j += 32) {
        unsigned m0 = csr[j + eg];
        unsigned m1 = csr[j + eg + 8];
        unsigned m2 = csr[j + eg + 16];
        unsigned m3 = csr[j + eg + 24];
        uint4 v0 = Hp4[(size_t)(m0 & 0xFFFFu) * 8 + fq];
        uint4 v1 = Hp4[(size_t)(m1 & 0xFFFFu) * 8 + fq];
        uint4 v2 = Hp4[(size_t)(m2 & 0xFFFFu) * 8 + fq];
        uint4 v3 = Hp4[(size_t)(m3 & 0xFFFFu) * 8 + fq];
        float w0 = __uint_as_float(m0 & 0xFFFF0000u);
        float w1 = __uint_as_float(m1 & 0xFFFF0000u);
        float w2 = __uint_as_float(m2 & 0xFFFF0000u);
        float w3 = __uint_as_float(m3 & 0xFFFF0000u);
        ACCUM(v0, w0) ACCUM(v1, w1) ACCUM(v2, w2) ACCUM(v3, w3)
    }
    for (; j + 8 <= end; j += 8) {
        unsigned m0 = csr[j + eg];
        float w0 = __uint_as_float(m0 & 0xFFFF0000u);
        uint4 v0 = Hp4[(size_t)(m0 & 0xFFFFu) * 8 + fq];
        ACCUM(v0, w0)
    }
    if (j < end) {
        int idx = j + eg;
        if (idx < end) {
            unsigned m0 = csr[idx];
            float w0 = __uint_as_float(m0 & 0xFFFF0000u);
            uint4 v0 = Hp4[(size_t)(m0 & 0xFFFFu) * 8 + fq];
            ACCUM(v0, w0)
        }
    }
#undef ACCUM
    // combine the 8 edge subgroups (lane bits 3,4,5)
#pragma unroll
    for (int off = 8; off < 64; off <<= 1) {
        a0 += __shfl_xor(a0, off, 64); a1 += __shfl_xor(a1, off, 64);
        a2 += __shfl_xor(a2, off, 64); a3 += __shfl_xor(a3, off, 64);
        a4 += __shfl_xor(a4, off, 64); a5 += __shfl_xor(a5, off, 64);
        a6 += __shfl_xor(a6, off, 64); a7 += __shfl_xor(a7, off, 64);
    }

    if (eg == 0) {
        uint4 sv = Hp4[(size_t)row * 8 + fq];   // self term (already dinv-scaled)
        float s0, s1, s2, s3, s4, s5, s6, s7;
        bf2(sv.x, s0, s1); bf2(sv.y, s2, s3);
        bf2(sv.z, s4, s5); bf2(sv.w, s6, s7);
        float o0 = dv * (a0 + s0), o1 = dv * (a1 + s1);
        float o2 = dv * (a2 + s2), o3 = dv * (a3 + s3);
        float o4 = dv * (a4 + s4), o5 = dv * (a5 + s5);
        float o6 = dv * (a6 + s6), o7 = dv * (a7 + s7);
        if (BIAS) {
            float4 b0 = ld4(b + fq * 8);
            float4 b1v = ld4(b + fq * 8 + 4);
            o0 += b0.x; o1 += b0.y; o2 += b0.z; o3 += b0.w;
            o4 += b1v.x; o5 += b1v.y; o6 += b1v.z; o7 += b1v.w;
        }
        if (OUTB) {
            uint4 pv = make_uint4(bfr(o0) | (bfr(o1) << 16),
                                  bfr(o2) | (bfr(o3) << 16),
                                  bfr(o4) | (bfr(o5) << 16),
                                  bfr(o6) | (bfr(o7) << 16));
            reinterpret_cast<uint4*>(out)[(size_t)row * 8 + fq] = pv;
        } else {
            float4* op = reinterpret_cast<float4*>((float*)out + (size_t)row * 64 + fq * 8);
            op[0] = make_float4(o0, o1, o2, o3);
            op[1] = make_float4(o4, o5, o6, o7);
        }
    }
}

// ---- fused dense on matrix cores (weights staged in padded LDS) ----
// hs = bf16(dinv * (relu(t1b @ W1 + b1) @ W2)); 64 rows per group, 4 waves x 16.
// Grid-strided; weights converted f32->bf16 during staging (no prep kernel).
// hT slices are wave-local -> no inner barriers needed.
__global__ __launch_bounds__(256) void densemfma_kernel(
        const unsigned short* __restrict__ t1b,   // [n][64] bf16
        const float* __restrict__ W1,             // [64][128] f32
        const float* __restrict__ b1,
        const float* __restrict__ W2,             // [128][64] f32
        const float* __restrict__ dinv,
        unsigned short* __restrict__ hs,          // [n][64] bf16 out
        int n) {
    __shared__ __align__(16) unsigned short W1s[128][68];   // [outcol][k], padded
    __shared__ __align__(16) unsigned short W2s[64][132];   // [outcol][k], padded
    __shared__ float b1s[128];
    __shared__ __align__(16) unsigned short hT[4][16][136];
    for (int i = threadIdx.x; i < 128 * 64; i += 256) {
        int c = i >> 6, k = i & 63;
        W1s[c][k] = (unsigned short)bfr(W1[k * 128 + c]);
    }
    for (int i = threadIdx.x; i < 64 * 128; i += 256) {
        int c = i >> 7, k = i & 127;
        W2s[c][k] = (unsigned short)bfr(W2[k * 64 + c]);
    }
    if (threadIdx.x < 128) b1s[threadIdx.x] = b1[threadIdx.x];
    __syncthreads();

    int wv = threadIdx.x >> 6;
    int l  = threadIdx.x & 63;
    int m  = l & 15, g = l >> 4;
    int ngrp = (n + 63) >> 6;
    for (int grp = blockIdx.x; grp < ngrp; grp += gridDim.x) {
        int R = grp * 64 + wv * 16;
        // ---- stage 1: C1 = t1b @ W1 (16 x 128), bias+relu -> hT tile ----
        short8v a0 = {0,0,0,0,0,0,0,0}, a1 = {0,0,0,0,0,0,0,0};
        int rowA = R + m;
        if (rowA < n) {
            a0 = *reinterpret_cast<const short8v*>(t1b + (size_t)rowA * 64 + 8 * g);
            a1 = *reinterpret_cast<const short8v*>(t1b + (size_t)rowA * 64 + 32 + 8 * g);
        }
#pragma unroll
        for (int ct = 0; ct < 8; ++ct) {
            short8v wb0 = *reinterpret_cast<const short8v*>(&W1s[ct * 16 + m][8 * g]);
            short8v wb1 = *reinterpret_cast<const short8v*>(&W1s[ct * 16 + m][32 + 8 * g]);
            f32x4 c = {0.f, 0.f, 0.f, 0.f};
            c = __builtin_amdgcn_mfma_f32_16x16x32_bf16(a0, wb0, c, 0, 0, 0);
            c = __builtin_amdgcn_mfma_f32_16x16x32_bf16(a1, wb1, c, 0, 0, 0);
            float bb = b1s[ct * 16 + m];
#pragma unroll
            for (int r = 0; r < 4; ++r) {
                float v = fmaxf(c[r] + bb, 0.f);
                hT[wv][4 * g + r][ct * 16 + m] = (unsigned short)bfr(v);
            }
        }
        // ---- stage 2: C2 = hT @ W2 (16 x 64); hT slice is wave-local ----
        f32x4 acc2[4];
#pragma unroll
        for (int ct = 0; ct < 4; ++ct) acc2[ct] = (f32x4){0.f, 0.f, 0.f, 0.f};
#pragma unroll
        for (int kk = 0; kk < 4; ++kk) {
            short8v ha = *reinterpret_cast<const short8v*>(&hT[wv][m][kk * 32 + 8 * g]);
#pragma unroll
            for (int ct = 0; ct < 4; ++ct) {
                short8v wb = *reinterpret_cast<const short8v*>(
                    &W2s[ct * 16 + m][kk * 32 + 8 * g]);
                acc2[ct] = __builtin_amdgcn_mfma_f32_16x16x32_bf16(ha, wb, acc2[ct], 0, 0, 0);
            }
        }
        // ---- epilogue: dinv-scale, bf16, transpose via wave-local hT, store ----
#pragma unroll
        for (int r = 0; r < 4; ++r) {
            int grow = R + 4 * g + r;
            float dv = (grow < n) ? dinv[grow] : 0.f;
#pragma unroll
            for (int ct = 0; ct < 4; ++ct)
                hT[wv][4 * g + r][ct * 16 + m] = (unsigned short)bfr(acc2[ct][r] * dv);
        }
        int growO = R + m;
        if (growO < n) {
            uint4 u0 = *reinterpret_cast<const uint4*>(&hT[wv][m][g * 16]);
            uint4 u1 = *reinterpret_cast<const uint4*>(&hT[wv][m][g * 16 + 8]);
            *reinterpret_cast<uint4*>(hs + (size_t)growO * 64 + g * 16) = u0;
            *reinterpret_cast<uint4*>(hs + (size_t)growO * 64 + g * 16 + 8) = u1;
        }
    }
}

extern "C" void kernel_launch(void* const* d_in, const int* in_sizes, int n_in,
                              void* d_out, int out_size, void* d_ws, size_t ws_size,
                              hipStream_t stream) {
    const float* z  = (const float*)d_in[0];
    const int*   ei = (const int*)d_in[1];
    const float* ea = (const float*)d_in[2];
    const float* W1 = (const float*)d_in[3];
    const float* b1 = (const float*)d_in[4];
    const float* W2 = (const float*)d_in[5];
    const float* b2 = (const float*)d_in[6];
    float* out = (float*)d_out;

    const int n = in_sizes[0] / 64;   // LAT = 64
    const int E = in_sizes[2];
    const int* src = ei;
    const int* dst = ei + E;
    const int NBKT = (n + NPB - 1) / NPB;   // 782 for n=50000 (<=1024 required)
    const int G1   = (E + CH - 1) / CH;     // chunk blocks (782 at E=1.6M)

    float* ws = (float*)d_ws;
    size_t p = 0;
    auto alloc = [&](size_t elems) { size_t o = p; p += (elems + 63) & ~63ull; return o; };
    float*    dinv   = ws + alloc(n);
    int*      rowptr = (int*)(ws + alloc((size_t)n + 1));
    int*      btot   = (int*)(ws + alloc(NBKT));
    unsigned* csr    = (unsigned*)(ws + alloc(E));        // u32 {src:u16, bf16 ew}
    unsigned short* t1b = (unsigned short*)(ws + alloc((size_t)n * 32)); // [n][64] bf16
    uint2*    zs     = (uint2*)(ws + alloc((size_t)n * 32));  // bf16 operand / hs
    // region X: tmp + hist (preprocessing only)
    float*    X      = ws + alloc((size_t)E * 2 + (size_t)NBKT * G1 + 64);
    int2*     tmp    = (int2*)X;                       // E int2
    int*      hist   = (int*)(X + (size_t)E * 2);      // NBKT*G1 ints
    (void)ws_size;

    // ---- preprocessing: counting sort by dst, zero global atomics ----
    hist_kernel<<<G1, 256, 0, stream>>>(dst, hist, E, G1, NBKT);
    bscan_kernel<<<NBKT, 64, 0, stream>>>(hist, btot, G1);
    scatter_kernel<<<G1, 256, 0, stream>>>(src, dst, ea, hist, btot, tmp, E, G1, NBKT);
    finalize_kernel<<<NBKT, 256, 0, stream>>>(tmp, btot, z, rowptr, dinv,
                                              csr, zs, n, E, NBKT);

    const int gblocks = (n + 3) / 4;
    // ---- layer 1 gather: t1b = bf16(Â z) ----
    gaggb_kernel<false, true><<<gblocks, 256, 0, stream>>>(rowptr, csr, dinv,
                                                           (const uint4*)zs,
                                                           nullptr, t1b, n);
    // ---- fused dense on MFMA: hs = bf16(dinv*(relu(t1b@W1+b1)@W2)) (reuses zs) ----
    densemfma_kernel<<<256, 256, 0, stream>>>(t1b, W1, b1, W2, dinv,
                                              (unsigned short*)zs, n);
    // ---- layer 2 gather: out = Â hs + b2 ----
    gaggb_kernel<true, false><<<gblocks, 256, 0, stream>>>(rowptr, csr, dinv,
                                                           (const uint4*)zs,
                                                           b2, out, n);
}

// Round 19
// 137.633 us; speedup vs baseline: 1.0555x; 1.0555x over previous
//
#include <hip/hip_runtime.h>

// 2-layer GCN, CSR-gather formulation, v19 (= v17 with CH=4096).
//   Â = D^{-1/2}(A+I)D^{-1/2},  out = Â(relu(Â z W1 + b1))W2 + b2
// layer1: t1b = bf16(Â z); dense: hs = bf16(dinv*(relu(t1b@W1+b1)@W2)) on MFMA;
// layer2: out = gather(hs) + b2.
// v6: CSR via counting sort — zero global atomics. v7: bf16 gather operand.
// v9: operand pre-scaled by dinv. v11: convs fused into finalize.
// v13/14: dense on matrix cores. v15/16: 32-edge MLP, 8x16B gather lanes.
// v17: 4B CSR entries (src:u16|bf16 ew), NPB=64.
// v19: CH=4096 — the untested middle of the config surface (NPB64/CH8192=143.7,
// NPB64/CH2048=145.3). R18 lesson: R17's "scatter 48us" was a profiling-pass
// artifact (didn't reconcile with the dur_us ledger); CH=2048 only added
// hist/scan overhead.

#define NPB 64    // nodes per fine bucket (dst & 63 is the in-bucket id)
#define CH  4096  // edges per chunk block in hist/scatter passes

typedef __attribute__((ext_vector_type(8))) short short8v;
typedef __attribute__((ext_vector_type(4))) float f32x4;

__device__ __forceinline__ float4 ld4(const float* p) {
    return *reinterpret_cast<const float4*>(p);
}

// round-to-nearest-even f32 -> bf16 (as ushort in low bits)
__device__ __forceinline__ unsigned bfr(float f) {
    unsigned u = __float_as_uint(f);
    return (u + 0x7FFFu + ((u >> 16) & 1u)) >> 16;
}
// unpack uint (2 bf16) -> 2 f32
__device__ __forceinline__ void bf2(unsigned v, float& lo, float& hi) {
    lo = __uint_as_float(v << 16);
    hi = __uint_as_float(v & 0xFFFF0000u);
}

// exclusive scan of btot[0..NBKT) into LDS bbs[] (blockDim=256, NBKT<=1024)
__device__ __forceinline__ void scan_btot(const int* __restrict__ btot, int NBKT,
                                          int* bbs, int* wtot) {
    int tid = threadIdx.x;
    int v[4];
    int s = 0;
#pragma unroll
    for (int q = 0; q < 4; ++q) {
        int i = 4 * tid + q;
        v[q] = (i < NBKT) ? btot[i] : 0;
        s += v[q];
    }
    int lane = tid & 63, wid = tid >> 6;
    int incl = s;
#pragma unroll
    for (int off = 1; off < 64; off <<= 1) {
        int u = __shfl_up(incl, off, 64);
        if (lane >= off) incl += u;
    }
    if (lane == 63) wtot[wid] = incl;
    __syncthreads();
    int woff = 0;
#pragma unroll
    for (int w = 0; w < 4; ++w) if (w < wid) woff += wtot[w];
    int ex = woff + incl - s;
#pragma unroll
    for (int q = 0; q < 4; ++q) {
        int i = 4 * tid + q;
        if (i < NBKT) bbs[i] = ex;
        ex += v[q];
    }
    __syncthreads();
}

// ---- K1: coarse histogram per chunk (LDS), bucket-major out: hist[b*G1+g] ----
__global__ __launch_bounds__(256) void hist_kernel(const int* __restrict__ dst,
                                                   int* __restrict__ hist,
                                                   int E, int G1, int NBKT) {
    __shared__ int lh[1024];
    for (int i = threadIdx.x; i < NBKT; i += 256) lh[i] = 0;
    __syncthreads();
    int g = blockIdx.x;
    int beg = g * CH, end = min(beg + CH, E);
    for (int j = beg + (int)threadIdx.x; j < end; j += 256)
        atomicAdd(&lh[dst[j] / NPB], 1);
    __syncthreads();
    for (int i = threadIdx.x; i < NBKT; i += 256) hist[(size_t)i * G1 + g] = lh[i];
}

// ---- K2: per-bucket exclusive scan across chunks (in place); btot[b] = total ----
__global__ __launch_bounds__(64) void bscan_kernel(int* __restrict__ hist,
                                                   int* __restrict__ btot, int G1) {
    int b = blockIdx.x;
    int* row = hist + (size_t)b * G1;
    int lane = threadIdx.x;
    int carry = 0;
    for (int g0 = 0; g0 < G1; g0 += 64) {
        int g = g0 + lane;
        int v = (g < G1) ? row[g] : 0;
        int incl = v;
#pragma unroll
        for (int off = 1; off < 64; off <<= 1) {
            int u = __shfl_up(incl, off, 64);
            if (lane >= off) incl += u;
        }
        if (g < G1) row[g] = carry + incl - v;
        carry += __shfl(incl, 63, 64);
    }
    if (lane == 0) btot[b] = carry;
}

// ---- K3: scatter edges into bucket-grouped tmp via LDS cursors (scan fused) ----
__global__ __launch_bounds__(256) void scatter_kernel(const int* __restrict__ src,
                                                      const int* __restrict__ dst,
                                                      const float* __restrict__ ew,
                                                      const int* __restrict__ hist,
                                                      const int* __restrict__ btot,
                                                      int2* __restrict__ tmp,
                                                      int E, int G1, int NBKT) {
    __shared__ int bbs[1024];
    __shared__ int wtot[4];
    __shared__ int cursor[1024];
    scan_btot(btot, NBKT, bbs, wtot);
    int g = blockIdx.x;
    for (int i = threadIdx.x; i < NBKT; i += 256)
        cursor[i] = bbs[i] + hist[(size_t)i * G1 + g];
    __syncthreads();
    int beg = g * CH, end = min(beg + CH, E);
    for (int j = beg + (int)threadIdx.x; j < end; j += 256) {
        int d = dst[j];
        int b = d / NPB;
        int pos = atomicAdd(&cursor[b], 1);
        tmp[pos] = make_int2(((d & (NPB - 1)) << 24) | src[j], __float_as_int(ew[j]));
    }
}

// ---- K4: per-bucket finalize: rowptr, dinv, final CSR u32 {src, bf16 ew}, zs ----
__global__ __launch_bounds__(256) void finalize_kernel(const int2* __restrict__ tmp,
                                                       const int* __restrict__ btot,
                                                       const float* __restrict__ z,
                                                       int* __restrict__ rowptr,
                                                       float* __restrict__ dinv,
                                                       unsigned* __restrict__ csr,
                                                       uint2* __restrict__ zs,
                                                       int n, int E, int NBKT) {
    __shared__ int bbs[1024];
    __shared__ int wsum_[4];
    __shared__ unsigned int hist[NPB];
    __shared__ float dvl[NPB];
    scan_btot(btot, NBKT, bbs, wsum_);
    int b = blockIdx.x;
    int base = bbs[b];
    int cnt  = btot[b];
    int tid  = threadIdx.x;
    if (tid < NPB) hist[tid] = 0;
    __syncthreads();
    // phase A: packed count (bits 24..31) + weighted degree (2^-14 fix, bits 0..23)
    for (int j = tid; j < cnt; j += 256) {
        int2 t = tmp[base + j];
        unsigned dlow = ((unsigned)t.x) >> 24;
        unsigned wfix = (unsigned)(__int_as_float(t.y) * 16384.0f);
        atomicAdd(&hist[dlow], (1u << 24) | wfix);
    }
    __syncthreads();
    // node-level exclusive scan (NPB=64 -> single wave 0)
    if (tid < NPB) {
        unsigned pk = hist[tid];
        int c = (int)(pk >> 24);
        int incl = c;
#pragma unroll
        for (int off = 1; off < 64; off <<= 1) {
            int u = __shfl_up(incl, off, 64);
            if (tid >= off) incl += u;
        }
        int excl = incl - c;
        int node = b * NPB + tid;
        float dv = 0.f;
        if (node < n) {
            rowptr[node] = base + excl;
            float wdeg = (float)(pk & 0xFFFFFFu) * (1.0f / 16384.0f);
            dv = rsqrtf(wdeg + 1.0f);
            dinv[node] = dv;
        }
        dvl[tid]  = dv;
        hist[tid] = (unsigned)excl;   // becomes cursor for phase B
    }
    if (b == 0 && tid == 0) rowptr[n] = E;
    __syncthreads();
    // phase B: place edges within bucket; csr entry = src | bf16(ew)<<16
    for (int j = tid; j < cnt; j += 256) {
        int2 t = tmp[base + j];
        unsigned dlow = ((unsigned)t.x) >> 24;
        unsigned srcv = (unsigned)(t.x & 0xFFFFFF);
        int lr = (int)atomicAdd(&hist[dlow], 1u);
        csr[base + lr] = srcv | (bfr(__int_as_float(t.y)) << 16);
    }
    // phase C (fused convs): zs[node] = bf16(dinv*z[node]) for this block's nodes
    for (int t = tid; t < NPB * 16; t += 256) {
        int li = t >> 4;
        int node = b * NPB + li;
        if (node < n) {
            int k = t & 15;
            float dv = dvl[li];
            float4 f = ld4(z + (size_t)node * 64 + k * 4);
            zs[(size_t)node * 16 + k] =
                make_uint2(bfr(dv * f.x) | (bfr(dv * f.y) << 16),
                           bfr(dv * f.z) | (bfr(dv * f.w) << 16));
        }
    }
}

// ---- gather-aggregate (F=64, bf16 pre-scaled operand): one wave per dst row ----
// Lane l: eg = l>>3 (8 edge subgroups), fq = l&7 (uint4 = 8 bf16 = 16B/lane).
// csr entry u32: src = lo16, bf16 ew = hi16. 32 edges in flight (4-deep).
// out[row] = (BIAS? b : 0) + dv * ( sum_j ew_j * Hp[src_j] + Hp[row] )
// OUTB: write result as bf16 [n][64] (uint4 per lane) instead of f32.
template<bool BIAS, bool OUTB>
__global__ __launch_bounds__(256) void gaggb_kernel(const int* __restrict__ rowptr,
                                                    const unsigned* __restrict__ csr,
                                                    const float* __restrict__ dinv,
                                                    const uint4* __restrict__ Hp4,
                                                    const float* __restrict__ b,
                                                    void* __restrict__ out, int n) {
    int row  = (blockIdx.x * 256 + threadIdx.x) >> 6;
    int lane = threadIdx.x & 63;
    if (row >= n) return;
    int eg = lane >> 3, fq = lane & 7;
    int beg = rowptr[row], end = rowptr[row + 1];
    float dv = dinv[row];

    float a0 = 0.f, a1 = 0.f, a2 = 0.f, a3 = 0.f;
    float a4 = 0.f, a5 = 0.f, a6 = 0.f, a7 = 0.f;
    float f0, f1, f2, f3, f4, f5, f6, f7;

#define ACCUM(V, W)                                            \
    bf2((V).x, f0, f1); bf2((V).y, f2, f3);                    \
    bf2((V).z, f4, f5); bf2((V).w, f6, f7);                    \
    a0 += (W) * f0; a1 += (W) * f1; a2 += (W) * f2; a3 += (W) * f3; \
    a4 += (W) * f4; a5 += (W) * f5; a6 += (W) * f6; a7 += (W) * f7;

    int j = beg;
    for (; j + 32 <= end; j += 32) {
        unsigned m0 = csr[j + eg];
        unsigned m1 = csr[j + eg + 8];
        unsigned m2 = csr[j + eg + 16];
        unsigned m3 = csr[j + eg + 24];
        uint4 v0 = Hp4[(size_t)(m0 & 0xFFFFu) * 8 + fq];
        uint4 v1 = Hp4[(size_t)(m1 & 0xFFFFu) * 8 + fq];
        uint4 v2 = Hp4[(size_t)(m2 & 0xFFFFu) * 8 + fq];
        uint4 v3 = Hp4[(size_t)(m3 & 0xFFFFu) * 8 + fq];
        float w0 = __uint_as_float(m0 & 0xFFFF0000u);
        float w1 = __uint_as_float(m1 & 0xFFFF0000u);
        float w2 = __uint_as_float(m2 & 0xFFFF0000u);
        float w3 = __uint_as_float(m3 & 0xFFFF0000u);
        ACCUM(v0, w0) ACCUM(v1, w1) ACCUM(v2, w2) ACCUM(v3, w3)
    }
    for (; j + 8 <= end; j += 8) {
        unsigned m0 = csr[j + eg];
        float w0 = __uint_as_float(m0 & 0xFFFF0000u);
        uint4 v0 = Hp4[(size_t)(m0 & 0xFFFFu) * 8 + fq];
        ACCUM(v0, w0)
    }
    if (j < end) {
        int idx = j + eg;
        if (idx < end) {
            unsigned m0 = csr[idx];
            float w0 = __uint_as_float(m0 & 0xFFFF0000u);
            uint4 v0 = Hp4[(size_t)(m0 & 0xFFFFu) * 8 + fq];
            ACCUM(v0, w0)
        }
    }
#undef ACCUM
    // combine the 8 edge subgroups (lane bits 3,4,5)
#pragma unroll
    for (int off = 8; off < 64; off <<= 1) {
        a0 += __shfl_xor(a0, off, 64); a1 += __shfl_xor(a1, off, 64);
        a2 += __shfl_xor(a2, off, 64); a3 += __shfl_xor(a3, off, 64);
        a4 += __shfl_xor(a4, off, 64); a5 += __shfl_xor(a5, off, 64);
        a6 += __shfl_xor(a6, off, 64); a7 += __shfl_xor(a7, off, 64);
    }

    if (eg == 0) {
        uint4 sv = Hp4[(size_t)row * 8 + fq];   // self term (already dinv-scaled)
        float s0, s1, s2, s3, s4, s5, s6, s7;
        bf2(sv.x, s0, s1); bf2(sv.y, s2, s3);
        bf2(sv.z, s4, s5); bf2(sv.w, s6, s7);
        float o0 = dv * (a0 + s0), o1 = dv * (a1 + s1);
        float o2 = dv * (a2 + s2), o3 = dv * (a3 + s3);
        float o4 = dv * (a4 + s4), o5 = dv * (a5 + s5);
        float o6 = dv * (a6 + s6), o7 = dv * (a7 + s7);
        if (BIAS) {
            float4 b0 = ld4(b + fq * 8);
            float4 b1v = ld4(b + fq * 8 + 4);
            o0 += b0.x; o1 += b0.y; o2 += b0.z; o3 += b0.w;
            o4 += b1v.x; o5 += b1v.y; o6 += b1v.z; o7 += b1v.w;
        }
        if (OUTB) {
            uint4 pv = make_uint4(bfr(o0) | (bfr(o1) << 16),
                                  bfr(o2) | (bfr(o3) << 16),
                                  bfr(o4) | (bfr(o5) << 16),
                                  bfr(o6) | (bfr(o7) << 16));
            reinterpret_cast<uint4*>(out)[(size_t)row * 8 + fq] = pv;
        } else {
            float4* op = reinterpret_cast<float4*>((float*)out + (size_t)row * 64 + fq * 8);
            op[0] = make_float4(o0, o1, o2, o3);
            op[1] = make_float4(o4, o5, o6, o7);
        }
    }
}

// ---- fused dense on matrix cores (weights staged in padded LDS) ----
// hs = bf16(dinv * (relu(t1b @ W1 + b1) @ W2)); 64 rows per group, 4 waves x 16.
// Grid-strided; weights converted f32->bf16 during staging (no prep kernel).
// hT slices are wave-local -> no inner barriers needed.
__global__ __launch_bounds__(256) void densemfma_kernel(
        const unsigned short* __restrict__ t1b,   // [n][64] bf16
        const float* __restrict__ W1,             // [64][128] f32
        const float* __restrict__ b1,
        const float* __restrict__ W2,             // [128][64] f32
        const float* __restrict__ dinv,
        unsigned short* __restrict__ hs,          // [n][64] bf16 out
        int n) {
    __shared__ __align__(16) unsigned short W1s[128][68];   // [outcol][k], padded
    __shared__ __align__(16) unsigned short W2s[64][132];   // [outcol][k], padded
    __shared__ float b1s[128];
    __shared__ __align__(16) unsigned short hT[4][16][136];
    for (int i = threadIdx.x; i < 128 * 64; i += 256) {
        int c = i >> 6, k = i & 63;
        W1s[c][k] = (unsigned short)bfr(W1[k * 128 + c]);
    }
    for (int i = threadIdx.x; i < 64 * 128; i += 256) {
        int c = i >> 7, k = i & 127;
        W2s[c][k] = (unsigned short)bfr(W2[k * 64 + c]);
    }
    if (threadIdx.x < 128) b1s[threadIdx.x] = b1[threadIdx.x];
    __syncthreads();

    int wv = threadIdx.x >> 6;
    int l  = threadIdx.x & 63;
    int m  = l & 15, g = l >> 4;
    int ngrp = (n + 63) >> 6;
    for (int grp = blockIdx.x; grp < ngrp; grp += gridDim.x) {
        int R = grp * 64 + wv * 16;
        // ---- stage 1: C1 = t1b @ W1 (16 x 128), bias+relu -> hT tile ----
        short8v a0 = {0,0,0,0,0,0,0,0}, a1 = {0,0,0,0,0,0,0,0};
        int rowA = R + m;
        if (rowA < n) {
            a0 = *reinterpret_cast<const short8v*>(t1b + (size_t)rowA * 64 + 8 * g);
            a1 = *reinterpret_cast<const short8v*>(t1b + (size_t)rowA * 64 + 32 + 8 * g);
        }
#pragma unroll
        for (int ct = 0; ct < 8; ++ct) {
            short8v wb0 = *reinterpret_cast<const short8v*>(&W1s[ct * 16 + m][8 * g]);
            short8v wb1 = *reinterpret_cast<const short8v*>(&W1s[ct * 16 + m][32 + 8 * g]);
            f32x4 c = {0.f, 0.f, 0.f, 0.f};
            c = __builtin_amdgcn_mfma_f32_16x16x32_bf16(a0, wb0, c, 0, 0, 0);
            c = __builtin_amdgcn_mfma_f32_16x16x32_bf16(a1, wb1, c, 0, 0, 0);
            float bb = b1s[ct * 16 + m];
#pragma unroll
            for (int r = 0; r < 4; ++r) {
                float v = fmaxf(c[r] + bb, 0.f);
                hT[wv][4 * g + r][ct * 16 + m] = (unsigned short)bfr(v);
            }
        }
        // ---- stage 2: C2 = hT @ W2 (16 x 64); hT slice is wave-local ----
        f32x4 acc2[4];
#pragma unroll
        for (int ct = 0; ct < 4; ++ct) acc2[ct] = (f32x4){0.f, 0.f, 0.f, 0.f};
#pragma unroll
        for (int kk = 0; kk < 4; ++kk) {
            short8v ha = *reinterpret_cast<const short8v*>(&hT[wv][m][kk * 32 + 8 * g]);
#pragma unroll
            for (int ct = 0; ct < 4; ++ct) {
                short8v wb = *reinterpret_cast<const short8v*>(
                    &W2s[ct * 16 + m][kk * 32 + 8 * g]);
                acc2[ct] = __builtin_amdgcn_mfma_f32_16x16x32_bf16(ha, wb, acc2[ct], 0, 0, 0);
            }
        }
        // ---- epilogue: dinv-scale, bf16, transpose via wave-local hT, store ----
#pragma unroll
        for (int r = 0; r < 4; ++r) {
            int grow = R + 4 * g + r;
            float dv = (grow < n) ? dinv[grow] : 0.f;
#pragma unroll
            for (int ct = 0; ct < 4; ++ct)
                hT[wv][4 * g + r][ct * 16 + m] = (unsigned short)bfr(acc2[ct][r] * dv);
        }
        int growO = R + m;
        if (growO < n) {
            uint4 u0 = *reinterpret_cast<const uint4*>(&hT[wv][m][g * 16]);
            uint4 u1 = *reinterpret_cast<const uint4*>(&hT[wv][m][g * 16 + 8]);
            *reinterpret_cast<uint4*>(hs + (size_t)growO * 64 + g * 16) = u0;
            *reinterpret_cast<uint4*>(hs + (size_t)growO * 64 + g * 16 + 8) = u1;
        }
    }
}

extern "C" void kernel_launch(void* const* d_in, const int* in_sizes, int n_in,
                              void* d_out, int out_size, void* d_ws, size_t ws_size,
                              hipStream_t stream) {
    const float* z  = (const float*)d_in[0];
    const int*   ei = (const int*)d_in[1];
    const float* ea = (const float*)d_in[2];
    const float* W1 = (const float*)d_in[3];
    const float* b1 = (const float*)d_in[4];
    const float* W2 = (const float*)d_in[5];
    const float* b2 = (const float*)d_in[6];
    float* out = (float*)d_out;

    const int n = in_sizes[0] / 64;   // LAT = 64
    const int E = in_sizes[2];
    const int* src = ei;
    const int* dst = ei + E;
    const int NBKT = (n + NPB - 1) / NPB;   // 782 for n=50000 (<=1024 required)
    const int G1   = (E + CH - 1) / CH;     // chunk blocks (391 at E=1.6M)

    float* ws = (float*)d_ws;
    size_t p = 0;
    auto alloc = [&](size_t elems) { size_t o = p; p += (elems + 63) & ~63ull; return o; };
    float*    dinv   = ws + alloc(n);
    int*      rowptr = (int*)(ws + alloc((size_t)n + 1));
    int*      btot   = (int*)(ws + alloc(NBKT));
    unsigned* csr    = (unsigned*)(ws + alloc(E));        // u32 {src:u16, bf16 ew}
    unsigned short* t1b = (unsigned short*)(ws + alloc((size_t)n * 32)); // [n][64] bf16
    uint2*    zs     = (uint2*)(ws + alloc((size_t)n * 32));  // bf16 operand / hs
    // region X: tmp + hist (preprocessing only)
    float*    X      = ws + alloc((size_t)E * 2 + (size_t)NBKT * G1 + 64);
    int2*     tmp    = (int2*)X;                       // E int2
    int*      hist   = (int*)(X + (size_t)E * 2);      // NBKT*G1 ints
    (void)ws_size;

    // ---- preprocessing: counting sort by dst, zero global atomics ----
    hist_kernel<<<G1, 256, 0, stream>>>(dst, hist, E, G1, NBKT);
    bscan_kernel<<<NBKT, 64, 0, stream>>>(hist, btot, G1);
    scatter_kernel<<<G1, 256, 0, stream>>>(src, dst, ea, hist, btot, tmp, E, G1, NBKT);
    finalize_kernel<<<NBKT, 256, 0, stream>>>(tmp, btot, z, rowptr, dinv,
                                              csr, zs, n, E, NBKT);

    const int gblocks = (n + 3) / 4;
    // ---- layer 1 gather: t1b = bf16(Â z) ----
    gaggb_kernel<false, true><<<gblocks, 256, 0, stream>>>(rowptr, csr, dinv,
                                                           (const uint4*)zs,
                                                           nullptr, t1b, n);
    // ---- fused dense on MFMA: hs = bf16(dinv*(relu(t1b@W1+b1)@W2)) (reuses zs) ----
    densemfma_kernel<<<256, 256, 0, stream>>>(t1b, W1, b1, W2, dinv,
                                              (unsigned short*)zs, n);
    // ---- layer 2 gather: out = Â hs + b2 ----
    gaggb_kernel<true, false><<<gblocks, 256, 0, stream>>>(rowptr, csr, dinv,
                                                           (const uint4*)zs,
                                                           b2, out, n);
}

// Round 20
// 135.395 us; speedup vs baseline: 1.0729x; 1.0165x over previous
//
#include <hip/hip_runtime.h>

// 2-layer GCN, CSR-gather formulation, v20.
//   Â = D^{-1/2}(A+I)D^{-1/2},  out = Â(relu(Â z W1 + b1))W2 + b2
// layer1: t1b = bf16(Â z); dense: hs = bf16(dinv*(relu(t1b@W1+b1)@W2)) on MFMA;
// layer2: out = gather(hs) + b2.
// v6: CSR via counting sort — zero global atomics. v7: bf16 gather operand.
// v9: operand pre-scaled by dinv. v11: convs fused into finalize.
// v13/14: dense on matrix cores. v15/16: 32-edge MLP, 8x16B gather lanes.
// v17: 4B CSR entries. v19: NPB=64, CH=4096 (config optimum).
// v20: scatter write-coalescing — hist transposed to [g][b] (hist writes +
// scatter cursor reads coalesced) and scatter stages its chunk bucket-major
// in LDS, then writes tmp LINEARLY (R19 counters: 41.6MB written for 12.8MB
// logical = 3.25x amplification from random 8B stores).

#define NPB 64    // nodes per fine bucket (dst & 63 is the in-bucket id)
#define CH  4096  // edges per chunk block in hist/scatter passes

typedef __attribute__((ext_vector_type(8))) short short8v;
typedef __attribute__((ext_vector_type(4))) float f32x4;

__device__ __forceinline__ float4 ld4(const float* p) {
    return *reinterpret_cast<const float4*>(p);
}

// round-to-nearest-even f32 -> bf16 (as ushort in low bits)
__device__ __forceinline__ unsigned bfr(float f) {
    unsigned u = __float_as_uint(f);
    return (u + 0x7FFFu + ((u >> 16) & 1u)) >> 16;
}
// unpack uint (2 bf16) -> 2 f32
__device__ __forceinline__ void bf2(unsigned v, float& lo, float& hi) {
    lo = __uint_as_float(v << 16);
    hi = __uint_as_float(v & 0xFFFF0000u);
}

// exclusive scan of srcarr[0..NBKT) into dstarr[] (blockDim=256, NBKT<=1024).
// srcarr may be global or LDS. Caller must barrier before if srcarr is LDS.
__device__ __forceinline__ void scan_any(const int* __restrict__ srcarr, int NBKT,
                                         int* dstarr, int* wtot) {
    int tid = threadIdx.x;
    int v[4];
    int s = 0;
#pragma unroll
    for (int q = 0; q < 4; ++q) {
        int i = 4 * tid + q;
        v[q] = (i < NBKT) ? srcarr[i] : 0;
        s += v[q];
    }
    int lane = tid & 63, wid = tid >> 6;
    int incl = s;
#pragma unroll
    for (int off = 1; off < 64; off <<= 1) {
        int u = __shfl_up(incl, off, 64);
        if (lane >= off) incl += u;
    }
    if (lane == 63) wtot[wid] = incl;
    __syncthreads();
    int woff = 0;
#pragma unroll
    for (int w = 0; w < 4; ++w) if (w < wid) woff += wtot[w];
    int ex = woff + incl - s;
#pragma unroll
    for (int q = 0; q < 4; ++q) {
        int i = 4 * tid + q;
        if (i < NBKT) dstarr[i] = ex;
        ex += v[q];
    }
    __syncthreads();
}

// ---- K1: coarse histogram per chunk (LDS), chunk-major out: hist[g*NBKT+b] ----
__global__ __launch_bounds__(256) void hist_kernel(const int* __restrict__ dst,
                                                   int* __restrict__ hist,
                                                   int E, int G1, int NBKT) {
    __shared__ int lh[1024];
    for (int i = threadIdx.x; i < NBKT; i += 256) lh[i] = 0;
    __syncthreads();
    int g = blockIdx.x;
    int beg = g * CH, end = min(beg + CH, E);
    for (int j = beg + (int)threadIdx.x; j < end; j += 256)
        atomicAdd(&lh[dst[j] / NPB], 1);
    __syncthreads();
    for (int i = threadIdx.x; i < NBKT; i += 256)
        hist[(size_t)g * NBKT + i] = lh[i];   // coalesced
}

// ---- K2: per-bucket exclusive scan across chunks (in place); btot[b] = total ----
// hist layout [g][b]: reads strided (L2-resident 1.2MB array, 782-block TLP).
__global__ __launch_bounds__(64) void bscan_kernel(int* __restrict__ hist,
                                                   int* __restrict__ btot,
                                                   int G1, int NBKT) {
    int b = blockIdx.x;
    int lane = threadIdx.x;
    int carry = 0;
    for (int g0 = 0; g0 < G1; g0 += 64) {
        int g = g0 + lane;
        int v = (g < G1) ? hist[(size_t)g * NBKT + b] : 0;
        int incl = v;
#pragma unroll
        for (int off = 1; off < 64; off <<= 1) {
            int u = __shfl_up(incl, off, 64);
            if (lane >= off) incl += u;
        }
        if (g < G1) hist[(size_t)g * NBKT + b] = carry + incl - v;
        carry += __shfl(incl, 63, 64);
    }
    if (lane == 0) btot[b] = carry;
}

// ---- K3: scatter edges into bucket-grouped tmp, LDS-staged for coalesced writes ----
__global__ __launch_bounds__(256) void scatter_kernel(const int* __restrict__ src,
                                                      const int* __restrict__ dst,
                                                      const float* __restrict__ ew,
                                                      const int* __restrict__ hist,
                                                      const int* __restrict__ btot,
                                                      int2* __restrict__ tmp,
                                                      int E, int G1, int NBKT) {
    __shared__ int bbs[1024];
    __shared__ int wtot[4];
    __shared__ int lcount[1024];
    __shared__ int lbase[1024];
    __shared__ int cursor[1024];
    __shared__ int gbase[1024];
    __shared__ int2 stg[CH];          // 32 KB staging
    int tid = threadIdx.x;
    scan_any(btot, NBKT, bbs, wtot);  // bucket bases (global)
    int g = blockIdx.x;
    for (int i = tid; i < NBKT; i += 256) lcount[i] = 0;
    __syncthreads();
    int beg = g * CH, end = min(beg + CH, E), cnt = end - beg;
    // pass 1: local bucket counts
    for (int j = beg + tid; j < end; j += 256)
        atomicAdd(&lcount[dst[j] / NPB], 1);
    __syncthreads();
    // local exclusive scan -> lbase; init cursor; global base per bucket
    scan_any(lcount, NBKT, lbase, wtot);
    for (int i = tid; i < NBKT; i += 256) {
        cursor[i] = lbase[i];
        gbase[i]  = bbs[i] + hist[(size_t)g * NBKT + i];   // coalesced read
    }
    __syncthreads();
    // pass 2: place edges bucket-major into LDS staging
    for (int j = beg + tid; j < end; j += 256) {
        int d = dst[j];
        int pos = atomicAdd(&cursor[d / NPB], 1);
        stg[pos] = make_int2((int)(((unsigned)d << 16) | (unsigned)src[j]),
                             __float_as_int(ew[j]));
    }
    __syncthreads();
    // pass 3: linear write-out; consecutive slots -> consecutive global positions
    for (int i = tid; i < cnt; i += 256) {
        int2 e = stg[i];
        unsigned dx = (unsigned)e.x;
        int b = (int)(dx >> 22);                 // d / 64
        int gpos = gbase[b] + (i - lbase[b]);
        int dlow = (int)((dx >> 16) & 63);
        tmp[gpos] = make_int2((dlow << 24) | (int)(dx & 0xFFFFu), e.y);
    }
}

// ---- K4: per-bucket finalize: rowptr, dinv, final CSR u32 {src, bf16 ew}, zs ----
__global__ __launch_bounds__(256) void finalize_kernel(const int2* __restrict__ tmp,
                                                       const int* __restrict__ btot,
                                                       const float* __restrict__ z,
                                                       int* __restrict__ rowptr,
                                                       float* __restrict__ dinv,
                                                       unsigned* __restrict__ csr,
                                                       uint2* __restrict__ zs,
                                                       int n, int E, int NBKT) {
    __shared__ int bbs[1024];
    __shared__ int wsum_[4];
    __shared__ unsigned int hist[NPB];
    __shared__ float dvl[NPB];
    scan_any(btot, NBKT, bbs, wsum_);
    int b = blockIdx.x;
    int base = bbs[b];
    int cnt  = btot[b];
    int tid  = threadIdx.x;
    if (tid < NPB) hist[tid] = 0;
    __syncthreads();
    // phase A: packed count (bits 24..31) + weighted degree (2^-14 fix, bits 0..23)
    for (int j = tid; j < cnt; j += 256) {
        int2 t = tmp[base + j];
        unsigned dlow = ((unsigned)t.x) >> 24;
        unsigned wfix = (unsigned)(__int_as_float(t.y) * 16384.0f);
        atomicAdd(&hist[dlow], (1u << 24) | wfix);
    }
    __syncthreads();
    // node-level exclusive scan (NPB=64 -> single wave 0)
    if (tid < NPB) {
        unsigned pk = hist[tid];
        int c = (int)(pk >> 24);
        int incl = c;
#pragma unroll
        for (int off = 1; off < 64; off <<= 1) {
            int u = __shfl_up(incl, off, 64);
            if (tid >= off) incl += u;
        }
        int excl = incl - c;
        int node = b * NPB + tid;
        float dv = 0.f;
        if (node < n) {
            rowptr[node] = base + excl;
            float wdeg = (float)(pk & 0xFFFFFFu) * (1.0f / 16384.0f);
            dv = rsqrtf(wdeg + 1.0f);
            dinv[node] = dv;
        }
        dvl[tid]  = dv;
        hist[tid] = (unsigned)excl;   // becomes cursor for phase B
    }
    if (b == 0 && tid == 0) rowptr[n] = E;
    __syncthreads();
    // phase B: place edges within bucket; csr entry = src | bf16(ew)<<16
    for (int j = tid; j < cnt; j += 256) {
        int2 t = tmp[base + j];
        unsigned dlow = ((unsigned)t.x) >> 24;
        unsigned srcv = (unsigned)(t.x & 0xFFFF);
        int lr = (int)atomicAdd(&hist[dlow], 1u);
        csr[base + lr] = srcv | (bfr(__int_as_float(t.y)) << 16);
    }
    // phase C (fused convs): zs[node] = bf16(dinv*z[node]) for this block's nodes
    for (int t = tid; t < NPB * 16; t += 256) {
        int li = t >> 4;
        int node = b * NPB + li;
        if (node < n) {
            int k = t & 15;
            float dv = dvl[li];
            float4 f = ld4(z + (size_t)node * 64 + k * 4);
            zs[(size_t)node * 16 + k] =
                make_uint2(bfr(dv * f.x) | (bfr(dv * f.y) << 16),
                           bfr(dv * f.z) | (bfr(dv * f.w) << 16));
        }
    }
}

// ---- gather-aggregate (F=64, bf16 pre-scaled operand): one wave per dst row ----
// Lane l: eg = l>>3 (8 edge subgroups), fq = l&7 (uint4 = 8 bf16 = 16B/lane).
// csr entry u32: src = lo16, bf16 ew = hi16. 32 edges in flight (4-deep).
// out[row] = (BIAS? b : 0) + dv * ( sum_j ew_j * Hp[src_j] + Hp[row] )
// OUTB: write result as bf16 [n][64] (uint4 per lane) instead of f32.
template<bool BIAS, bool OUTB>
__global__ __launch_bounds__(256) void gaggb_kernel(const int* __restrict__ rowptr,
                                                    const unsigned* __restrict__ csr,
                                                    const float* __restrict__ dinv,
                                                    const uint4* __restrict__ Hp4,
                                                    const float* __restrict__ b,
                                                    void* __restrict__ out, int n) {
    int row  = (blockIdx.x * 256 + threadIdx.x) >> 6;
    int lane = threadIdx.x & 63;
    if (row >= n) return;
    int eg = lane >> 3, fq = lane & 7;
    int beg = rowptr[row], end = rowptr[row + 1];
    float dv = dinv[row];

    float a0 = 0.f, a1 = 0.f, a2 = 0.f, a3 = 0.f;
    float a4 = 0.f, a5 = 0.f, a6 = 0.f, a7 = 0.f;
    float f0, f1, f2, f3, f4, f5, f6, f7;

#define ACCUM(V, W)                                            \
    bf2((V).x, f0, f1); bf2((V).y, f2, f3);                    \
    bf2((V).z, f4, f5); bf2((V).w, f6, f7);                    \
    a0 += (W) * f0; a1 += (W) * f1; a2 += (W) * f2; a3 += (W) * f3; \
    a4 += (W) * f4; a5 += (W) * f5; a6 += (W) * f6; a7 += (W) * f7;

    int j = beg;
    for (; j + 32 <= end; j += 32) {
        unsigned m0 = csr[j + eg];
        unsigned m1 = csr[j + eg + 8];
        unsigned m2 = csr[j + eg + 16];
        unsigned m3 = csr[j + eg + 24];
        uint4 v0 = Hp4[(size_t)(m0 & 0xFFFFu) * 8 + fq];
        uint4 v1 = Hp4[(size_t)(m1 & 0xFFFFu) * 8 + fq];
        uint4 v2 = Hp4[(size_t)(m2 & 0xFFFFu) * 8 + fq];
        uint4 v3 = Hp4[(size_t)(m3 & 0xFFFFu) * 8 + fq];
        float w0 = __uint_as_float(m0 & 0xFFFF0000u);
        float w1 = __uint_as_float(m1 & 0xFFFF0000u);
        float w2 = __uint_as_float(m2 & 0xFFFF0000u);
        float w3 = __uint_as_float(m3 & 0xFFFF0000u);
        ACCUM(v0, w0) ACCUM(v1, w1) ACCUM(v2, w2) ACCUM(v3, w3)
    }
    for (; j + 8 <= end; j += 8) {
        unsigned m0 = csr[j + eg];
        float w0 = __uint_as_float(m0 & 0xFFFF0000u);
        uint4 v0 = Hp4[(size_t)(m0 & 0xFFFFu) * 8 + fq];
        ACCUM(v0, w0)
    }
    if (j < end) {
        int idx = j + eg;
        if (idx < end) {
            unsigned m0 = csr[idx];
            float w0 = __uint_as_float(m0 & 0xFFFF0000u);
            uint4 v0 = Hp4[(size_t)(m0 & 0xFFFFu) * 8 + fq];
            ACCUM(v0, w0)
        }
    }
#undef ACCUM
    // combine the 8 edge subgroups (lane bits 3,4,5)
#pragma unroll
    for (int off = 8; off < 64; off <<= 1) {
        a0 += __shfl_xor(a0, off, 64); a1 += __shfl_xor(a1, off, 64);
        a2 += __shfl_xor(a2, off, 64); a3 += __shfl_xor(a3, off, 64);
        a4 += __shfl_xor(a4, off, 64); a5 += __shfl_xor(a5, off, 64);
        a6 += __shfl_xor(a6, off, 64); a7 += __shfl_xor(a7, off, 64);
    }

    if (eg == 0) {
        uint4 sv = Hp4[(size_t)row * 8 + fq];   // self term (already dinv-scaled)
        float s0, s1, s2, s3, s4, s5, s6, s7;
        bf2(sv.x, s0, s1); bf2(sv.y, s2, s3);
        bf2(sv.z, s4, s5); bf2(sv.w, s6, s7);
        float o0 = dv * (a0 + s0), o1 = dv * (a1 + s1);
        float o2 = dv * (a2 + s2), o3 = dv * (a3 + s3);
        float o4 = dv * (a4 + s4), o5 = dv * (a5 + s5);
        float o6 = dv * (a6 + s6), o7 = dv * (a7 + s7);
        if (BIAS) {
            float4 b0 = ld4(b + fq * 8);
            float4 b1v = ld4(b + fq * 8 + 4);
            o0 += b0.x; o1 += b0.y; o2 += b0.z; o3 += b0.w;
            o4 += b1v.x; o5 += b1v.y; o6 += b1v.z; o7 += b1v.w;
        }
        if (OUTB) {
            uint4 pv = make_uint4(bfr(o0) | (bfr(o1) << 16),
                                  bfr(o2) | (bfr(o3) << 16),
                                  bfr(o4) | (bfr(o5) << 16),
                                  bfr(o6) | (bfr(o7) << 16));
            reinterpret_cast<uint4*>(out)[(size_t)row * 8 + fq] = pv;
        } else {
            float4* op = reinterpret_cast<float4*>((float*)out + (size_t)row * 64 + fq * 8);
            op[0] = make_float4(o0, o1, o2, o3);
            op[1] = make_float4(o4, o5, o6, o7);
        }
    }
}

// ---- fused dense on matrix cores (weights staged in padded LDS) ----
// hs = bf16(dinv * (relu(t1b @ W1 + b1) @ W2)); 64 rows per group, 4 waves x 16.
// Grid-strided; weights converted f32->bf16 during staging (no prep kernel).
// hT slices are wave-local -> no inner barriers needed.
__global__ __launch_bounds__(256) void densemfma_kernel(
        const unsigned short* __restrict__ t1b,   // [n][64] bf16
        const float* __restrict__ W1,             // [64][128] f32
        const float* __restrict__ b1,
        const float* __restrict__ W2,             // [128][64] f32
        const float* __restrict__ dinv,
        unsigned short* __restrict__ hs,          // [n][64] bf16 out
        int n) {
    __shared__ __align__(16) unsigned short W1s[128][68];   // [outcol][k], padded
    __shared__ __align__(16) unsigned short W2s[64][132];   // [outcol][k], padded
    __shared__ float b1s[128];
    __shared__ __align__(16) unsigned short hT[4][16][136];
    for (int i = threadIdx.x; i < 128 * 64; i += 256) {
        int c = i >> 6, k = i & 63;
        W1s[c][k] = (unsigned short)bfr(W1[k * 128 + c]);
    }
    for (int i = threadIdx.x; i < 64 * 128; i += 256) {
        int c = i >> 7, k = i & 127;
        W2s[c][k] = (unsigned short)bfr(W2[k * 64 + c]);
    }
    if (threadIdx.x < 128) b1s[threadIdx.x] = b1[threadIdx.x];
    __syncthreads();

    int wv = threadIdx.x >> 6;
    int l  = threadIdx.x & 63;
    int m  = l & 15, g = l >> 4;
    int ngrp = (n + 63) >> 6;
    for (int grp = blockIdx.x; grp < ngrp; grp += gridDim.x) {
        int R = grp * 64 + wv * 16;
        // ---- stage 1: C1 = t1b @ W1 (16 x 128), bias+relu -> hT tile ----
        short8v a0 = {0,0,0,0,0,0,0,0}, a1 = {0,0,0,0,0,0,0,0};
        int rowA = R + m;
        if (rowA < n) {
            a0 = *reinterpret_cast<const short8v*>(t1b + (size_t)rowA * 64 + 8 * g);
            a1 = *reinterpret_cast<const short8v*>(t1b + (size_t)rowA * 64 + 32 + 8 * g);
        }
#pragma unroll
        for (int ct = 0; ct < 8; ++ct) {
            short8v wb0 = *reinterpret_cast<const short8v*>(&W1s[ct * 16 + m][8 * g]);
            short8v wb1 = *reinterpret_cast<const short8v*>(&W1s[ct * 16 + m][32 + 8 * g]);
            f32x4 c = {0.f, 0.f, 0.f, 0.f};
            c = __builtin_amdgcn_mfma_f32_16x16x32_bf16(a0, wb0, c, 0, 0, 0);
            c = __builtin_amdgcn_mfma_f32_16x16x32_bf16(a1, wb1, c, 0, 0, 0);
            float bb = b1s[ct * 16 + m];
#pragma unroll
            for (int r = 0; r < 4; ++r) {
                float v = fmaxf(c[r] + bb, 0.f);
                hT[wv][4 * g + r][ct * 16 + m] = (unsigned short)bfr(v);
            }
        }
        // ---- stage 2: C2 = hT @ W2 (16 x 64); hT slice is wave-local ----
        f32x4 acc2[4];
#pragma unroll
        for (int ct = 0; ct < 4; ++ct) acc2[ct] = (f32x4){0.f, 0.f, 0.f, 0.f};
#pragma unroll
        for (int kk = 0; kk < 4; ++kk) {
            short8v ha = *reinterpret_cast<const short8v*>(&hT[wv][m][kk * 32 + 8 * g]);
#pragma unroll
            for (int ct = 0; ct < 4; ++ct) {
                short8v wb = *reinterpret_cast<const short8v*>(
                    &W2s[ct * 16 + m][kk * 32 + 8 * g]);
                acc2[ct] = __builtin_amdgcn_mfma_f32_16x16x32_bf16(ha, wb, acc2[ct], 0, 0, 0);
            }
        }
        // ---- epilogue: dinv-scale, bf16, transpose via wave-local hT, store ----
#pragma unroll
        for (int r = 0; r < 4; ++r) {
            int grow = R + 4 * g + r;
            float dv = (grow < n) ? dinv[grow] : 0.f;
#pragma unroll
            for (int ct = 0; ct < 4; ++ct)
                hT[wv][4 * g + r][ct * 16 + m] = (unsigned short)bfr(acc2[ct][r] * dv);
        }
        int growO = R + m;
        if (growO < n) {
            uint4 u0 = *reinterpret_cast<const uint4*>(&hT[wv][m][g * 16]);
            uint4 u1 = *reinterpret_cast<const uint4*>(&hT[wv][m][g * 16 + 8]);
            *reinterpret_cast<uint4*>(hs + (size_t)growO * 64 + g * 16) = u0;
            *reinterpret_cast<uint4*>(hs + (size_t)growO * 64 + g * 16 + 8) = u1;
        }
    }
}

extern "C" void kernel_launch(void* const* d_in, const int* in_sizes, int n_in,
                              void* d_out, int out_size, void* d_ws, size_t ws_size,
                              hipStream_t stream) {
    const float* z  = (const float*)d_in[0];
    const int*   ei = (const int*)d_in[1];
    const float* ea = (const float*)d_in[2];
    const float* W1 = (const float*)d_in[3];
    const float* b1 = (const float*)d_in[4];
    const float* W2 = (const float*)d_in[5];
    const float* b2 = (const float*)d_in[6];
    float* out = (float*)d_out;

    const int n = in_sizes[0] / 64;   // LAT = 64
    const int E = in_sizes[2];
    const int* src = ei;
    const int* dst = ei + E;
    const int NBKT = (n + NPB - 1) / NPB;   // 782 for n=50000 (<=1024 required)
    const int G1   = (E + CH - 1) / CH;     // chunk blocks (391 at E=1.6M)

    float* ws = (float*)d_ws;
    size_t p = 0;
    auto alloc = [&](size_t elems) { size_t o = p; p += (elems + 63) & ~63ull; return o; };
    float*    dinv   = ws + alloc(n);
    int*      rowptr = (int*)(ws + alloc((size_t)n + 1));
    int*      btot   = (int*)(ws + alloc(NBKT));
    unsigned* csr    = (unsigned*)(ws + alloc(E));        // u32 {src:u16, bf16 ew}
    unsigned short* t1b = (unsigned short*)(ws + alloc((size_t)n * 32)); // [n][64] bf16
    uint2*    zs     = (uint2*)(ws + alloc((size_t)n * 32));  // bf16 operand / hs
    // region X: tmp + hist (preprocessing only)
    float*    X      = ws + alloc((size_t)E * 2 + (size_t)NBKT * G1 + 64);
    int2*     tmp    = (int2*)X;                       // E int2
    int*      hist   = (int*)(X + (size_t)E * 2);      // G1*NBKT ints, [g][b]
    (void)ws_size;

    // ---- preprocessing: counting sort by dst, zero global atomics ----
    hist_kernel<<<G1, 256, 0, stream>>>(dst, hist, E, G1, NBKT);
    bscan_kernel<<<NBKT, 64, 0, stream>>>(hist, btot, G1, NBKT);
    scatter_kernel<<<G1, 256, 0, stream>>>(src, dst, ea, hist, btot, tmp, E, G1, NBKT);
    finalize_kernel<<<NBKT, 256, 0, stream>>>(tmp, btot, z, rowptr, dinv,
                                              csr, zs, n, E, NBKT);

    const int gblocks = (n + 3) / 4;
    // ---- layer 1 gather: t1b = bf16(Â z) ----
    gaggb_kernel<false, true><<<gblocks, 256, 0, stream>>>(rowptr, csr, dinv,
                                                           (const uint4*)zs,
                                                           nullptr, t1b, n);
    // ---- fused dense on MFMA: hs = bf16(dinv*(relu(t1b@W1+b1)@W2)) (reuses zs) ----
    densemfma_kernel<<<256, 256, 0, stream>>>(t1b, W1, b1, W2, dinv,
                                              (unsigned short*)zs, n);
    // ---- layer 2 gather: out = Â hs + b2 ----
    gaggb_kernel<true, false><<<gblocks, 256, 0, stream>>>(rowptr, csr, dinv,
                                                           (const uint4*)zs,
                                                           b2, out, n);
}